// Round 1
// baseline (4029.858 us; speedup 1.0000x reference)
//
#include <hip/hip_runtime.h>
#include <math.h>

namespace {
constexpr int kBT = 1024;   // B*T
constexpr int kD1 = 256;
constexpr int kD2 = 128;
constexpr int kDM = 1024;
constexpr int kV  = 32000;
constexpr int kK  = 4;

constexpr int ROWS_H   = kK * kDM;              // 4096
constexpr int ROWS_U   = kK * kD2;              // 512
constexpr int ROWS_ALL = ROWS_H + ROWS_U + kK;  // 4612
constexpr int HALF_ROWS = ROWS_ALL / 2;         // 2306

// ---------------------------------------------------------------------------
// Kernel 1: prep. hc[bt][k*DM+d] = tanh(H[k,d,:]·gc[bt,:])
//                 tU[bt][k*D2+j] = tanh(U[k,j,:]·gc[bt,:])
//                 ug[bt*4+k]     =      u[k,:]·gc[bt,:]
// Each block: 8 consecutive bt rows staged in LDS; threads own W-rows.
// ---------------------------------------------------------------------------
__global__ __launch_bounds__(256) void prep_kernel(
    const float* __restrict__ gc, const float* __restrict__ Hm,
    const float* __restrict__ Um, const float* __restrict__ um,
    float* __restrict__ hc, float* __restrict__ tUo, float* __restrict__ ug)
{
    __shared__ float sgc[8][kD1];
    const int btBase = blockIdx.x * 8;
    for (int idx = threadIdx.x; idx < 8 * kD1; idx += 256)
        sgc[idx / kD1][idx % kD1] = gc[(size_t)btBase * kD1 + idx];
    __syncthreads();

    const int rStart = blockIdx.y * HALF_ROWS;
    const int rEnd   = rStart + HALF_ROWS;
    for (int r = rStart + (int)threadIdx.x; r < rEnd; r += 256) {
        const float* wrow;
        if (r < ROWS_H)               wrow = Hm + (size_t)r * kD1;
        else if (r < ROWS_H + ROWS_U) wrow = Um + (size_t)(r - ROWS_H) * kD1;
        else                          wrow = um + (size_t)(r - ROWS_H - ROWS_U) * kD1;

        float acc[8] = {0.f,0.f,0.f,0.f,0.f,0.f,0.f,0.f};
        for (int i = 0; i < kD1; i += 4) {
            const float4 w = *reinterpret_cast<const float4*>(wrow + i);
            #pragma unroll
            for (int b = 0; b < 8; ++b) {
                const float4 g = *reinterpret_cast<const float4*>(&sgc[b][i]);
                acc[b] = fmaf(w.x, g.x, acc[b]);
                acc[b] = fmaf(w.y, g.y, acc[b]);
                acc[b] = fmaf(w.z, g.z, acc[b]);
                acc[b] = fmaf(w.w, g.w, acc[b]);
            }
        }
        #pragma unroll
        for (int b = 0; b < 8; ++b) {
            const int bt = btBase + b;
            if (r < ROWS_H)
                hc[(size_t)bt * ROWS_H + r] = tanhf(acc[b]);
            else if (r < ROWS_H + ROWS_U)
                tUo[(size_t)bt * ROWS_U + (r - ROWS_H)] = tanhf(acc[b]);
            else
                ug[bt * kK + (r - ROWS_H - ROWS_U)] = acc[b];
        }
    }
}

// ---------------------------------------------------------------------------
// Kernel 2: fused gate-GEMM (D2) + dots-GEMM (DM) + sigmoid-tree -> logits.
// Tile: 32 bt x 64 v per block of 256 threads.
// Thread (tx=tid&15, ty=tid>>4) owns bt in {ty, ty+16}, v in {tx*4..tx*4+3},
// with K=4 accumulator planes each.
// LDS A-tile transposed: sA[d][bt_local*4+k]; B-tile: sB[d][v_local].
// ---------------------------------------------------------------------------
__global__ __launch_bounds__(256) void fused_kernel(
    const float* __restrict__ hc, const float* __restrict__ tUi,
    const float* __restrict__ ug, const float* __restrict__ vmat,
    const float* __restrict__ bmat, const float* __restrict__ emb,
    float* __restrict__ out)
{
    __shared__ float sA[32][128];  // 16 KB
    __shared__ float sB[32][64];   //  8 KB
    const int btBase = blockIdx.x * 32;
    const int vBase  = blockIdx.y * 64;
    const int tid = threadIdx.x;
    const int tx = tid & 15;
    const int ty = tid >> 4;

    float acc[2][4][4];
    #pragma unroll
    for (int a = 0; a < 2; ++a)
        #pragma unroll
        for (int k = 0; k < 4; ++k)
            #pragma unroll
            for (int j = 0; j < 4; ++j) acc[a][k][j] = 0.f;

    // -------- phase 1: lv = v · tU over D2 --------
    for (int dBase = 0; dBase < kD2; dBase += 32) {
        {   // stage A (tU): 128 rows x 32 cols, transposed into sA[d][row]
            const int row = tid >> 1;
            const int c0  = (tid & 1) * 16;
            const int btl = row >> 2, k = row & 3;
            const float* src = tUi + (size_t)(btBase + btl) * ROWS_U + k * kD2 + dBase + c0;
            #pragma unroll
            for (int it = 0; it < 4; ++it) {
                const float4 w = *reinterpret_cast<const float4*>(src + it * 4);
                sA[c0 + it*4 + 0][row] = w.x;
                sA[c0 + it*4 + 1][row] = w.y;
                sA[c0 + it*4 + 2][row] = w.z;
                sA[c0 + it*4 + 3][row] = w.w;
            }
        }
        {   // stage B (vmat): 64 rows x 32 cols, transposed into sB[d][v]
            #pragma unroll
            for (int it = 0; it < 2; ++it) {
                const int idx = tid + it * 256;
                const int vl = idx >> 3, dq = (idx & 7) * 4;
                const float4 w = *reinterpret_cast<const float4*>(
                    vmat + (size_t)(vBase + vl) * kD2 + dBase + dq);
                sB[dq+0][vl] = w.x; sB[dq+1][vl] = w.y;
                sB[dq+2][vl] = w.z; sB[dq+3][vl] = w.w;
            }
        }
        __syncthreads();
        #pragma unroll
        for (int d = 0; d < 32; ++d) {
            const float4 a0 = *reinterpret_cast<const float4*>(&sA[d][ty * 4]);
            const float4 a1 = *reinterpret_cast<const float4*>(&sA[d][ty * 4 + 64]);
            const float4 bv = *reinterpret_cast<const float4*>(&sB[d][tx * 4]);
            const float av0[4] = {a0.x, a0.y, a0.z, a0.w};
            const float av1[4] = {a1.x, a1.y, a1.z, a1.w};
            const float bvv[4] = {bv.x, bv.y, bv.z, bv.w};
            #pragma unroll
            for (int k = 0; k < 4; ++k)
                #pragma unroll
                for (int j = 0; j < 4; ++j) {
                    acc[0][k][j] = fmaf(av0[k], bvv[j], acc[0][k][j]);
                    acc[1][k][j] = fmaf(av1[k], bvv[j], acc[1][k][j]);
                }
        }
        __syncthreads();
    }

    // -------- gate math: lv -> pi --------
    float pi[2][4][4];
    #pragma unroll
    for (int b2 = 0; b2 < 2; ++b2) {
        const int bt = btBase + ty + b2 * 16;
        const float4 ugv = *reinterpret_cast<const float4*>(ug + bt * kK);
        #pragma unroll
        for (int j = 0; j < 4; ++j) {
            const int vg = vBase + tx * 4 + j;
            const float4 bb = *reinterpret_cast<const float4*>(bmat + (size_t)vg * kK);
            const float l0 = acc[b2][0][j] + ugv.x + bb.x;
            const float l1 = acc[b2][1][j] + ugv.y + bb.y;
            const float l2 = acc[b2][2][j] + ugv.z + bb.z;
            const float g0 = 1.f / (1.f + __expf(-l0));
            const float g1 = 1.f / (1.f + __expf(-l1));
            const float g2 = 1.f / (1.f + __expf(-l2));
            pi[b2][0][j] = g0 * g1;
            pi[b2][1][j] = g0 * (1.f - g1);
            pi[b2][2][j] = (1.f - g0) * g2;
            pi[b2][3][j] = (1.f - g0) * (1.f - g2);
        }
    }

    // -------- phase 2: dots = hc · emb over DM --------
    #pragma unroll
    for (int a = 0; a < 2; ++a)
        #pragma unroll
        for (int k = 0; k < 4; ++k)
            #pragma unroll
            for (int j = 0; j < 4; ++j) acc[a][k][j] = 0.f;

    for (int dBase = 0; dBase < kDM; dBase += 32) {
        {   // stage A (hc)
            const int row = tid >> 1;
            const int c0  = (tid & 1) * 16;
            const int btl = row >> 2, k = row & 3;
            const float* src = hc + (size_t)(btBase + btl) * ROWS_H + k * kDM + dBase + c0;
            #pragma unroll
            for (int it = 0; it < 4; ++it) {
                const float4 w = *reinterpret_cast<const float4*>(src + it * 4);
                sA[c0 + it*4 + 0][row] = w.x;
                sA[c0 + it*4 + 1][row] = w.y;
                sA[c0 + it*4 + 2][row] = w.z;
                sA[c0 + it*4 + 3][row] = w.w;
            }
        }
        {   // stage B (emb)
            #pragma unroll
            for (int it = 0; it < 2; ++it) {
                const int idx = tid + it * 256;
                const int vl = idx >> 3, dq = (idx & 7) * 4;
                const float4 w = *reinterpret_cast<const float4*>(
                    emb + (size_t)(vBase + vl) * kDM + dBase + dq);
                sB[dq+0][vl] = w.x; sB[dq+1][vl] = w.y;
                sB[dq+2][vl] = w.z; sB[dq+3][vl] = w.w;
            }
        }
        __syncthreads();
        #pragma unroll
        for (int d = 0; d < 32; ++d) {
            const float4 a0 = *reinterpret_cast<const float4*>(&sA[d][ty * 4]);
            const float4 a1 = *reinterpret_cast<const float4*>(&sA[d][ty * 4 + 64]);
            const float4 bv = *reinterpret_cast<const float4*>(&sB[d][tx * 4]);
            const float av0[4] = {a0.x, a0.y, a0.z, a0.w};
            const float av1[4] = {a1.x, a1.y, a1.z, a1.w};
            const float bvv[4] = {bv.x, bv.y, bv.z, bv.w};
            #pragma unroll
            for (int k = 0; k < 4; ++k)
                #pragma unroll
                for (int j = 0; j < 4; ++j) {
                    acc[0][k][j] = fmaf(av0[k], bvv[j], acc[0][k][j]);
                    acc[1][k][j] = fmaf(av1[k], bvv[j], acc[1][k][j]);
                }
        }
        __syncthreads();
    }

    // -------- epilogue: logits = sum_k pi*dots --------
    #pragma unroll
    for (int b2 = 0; b2 < 2; ++b2) {
        const int bt = btBase + ty + b2 * 16;
        float4 o;
        o.x = pi[b2][0][0]*acc[b2][0][0] + pi[b2][1][0]*acc[b2][1][0]
            + pi[b2][2][0]*acc[b2][2][0] + pi[b2][3][0]*acc[b2][3][0];
        o.y = pi[b2][0][1]*acc[b2][0][1] + pi[b2][1][1]*acc[b2][1][1]
            + pi[b2][2][1]*acc[b2][2][1] + pi[b2][3][1]*acc[b2][3][1];
        o.z = pi[b2][0][2]*acc[b2][0][2] + pi[b2][1][2]*acc[b2][1][2]
            + pi[b2][2][2]*acc[b2][2][2] + pi[b2][3][2]*acc[b2][3][2];
        o.w = pi[b2][0][3]*acc[b2][0][3] + pi[b2][1][3]*acc[b2][1][3]
            + pi[b2][2][3]*acc[b2][2][3] + pi[b2][3][3]*acc[b2][3][3];
        *reinterpret_cast<float4*>(out + (size_t)bt * kV + vBase + tx * 4) = o;
    }
}

// ---------------------------------------------------------------------------
// Kernel 3: row softmax over V, in place on d_out. One block per row.
// ---------------------------------------------------------------------------
__global__ __launch_bounds__(256) void softmax_kernel(float* __restrict__ out)
{
    __shared__ float red[4];
    float* row = out + (size_t)blockIdx.x * kV;
    const int tid = threadIdx.x;

    float mx = -1e30f;
    for (int i = tid * 4; i < kV; i += 1024) {
        const float4 x = *reinterpret_cast<const float4*>(row + i);
        mx = fmaxf(mx, fmaxf(fmaxf(x.x, x.y), fmaxf(x.z, x.w)));
    }
    #pragma unroll
    for (int o = 1; o < 64; o <<= 1) mx = fmaxf(mx, __shfl_xor(mx, o));
    if ((tid & 63) == 0) red[tid >> 6] = mx;
    __syncthreads();
    mx = fmaxf(fmaxf(red[0], red[1]), fmaxf(red[2], red[3]));
    __syncthreads();

    float s = 0.f;
    for (int i = tid * 4; i < kV; i += 1024) {
        const float4 x = *reinterpret_cast<const float4*>(row + i);
        s += __expf(x.x - mx) + __expf(x.y - mx) + __expf(x.z - mx) + __expf(x.w - mx);
    }
    #pragma unroll
    for (int o = 1; o < 64; o <<= 1) s += __shfl_xor(s, o);
    if ((tid & 63) == 0) red[tid >> 6] = s;
    __syncthreads();
    s = red[0] + red[1] + red[2] + red[3];
    const float inv = 1.f / s;

    for (int i = tid * 4; i < kV; i += 1024) {
        const float4 x = *reinterpret_cast<const float4*>(row + i);
        float4 y;
        y.x = __expf(x.x - mx) * inv;
        y.y = __expf(x.y - mx) * inv;
        y.z = __expf(x.z - mx) * inv;
        y.w = __expf(x.w - mx) * inv;
        *reinterpret_cast<float4*>(row + i) = y;
    }
}

} // namespace

extern "C" void kernel_launch(void* const* d_in, const int* in_sizes, int n_in,
                              void* d_out, int out_size, void* d_ws, size_t ws_size,
                              hipStream_t stream)
{
    (void)in_sizes; (void)n_in; (void)out_size; (void)ws_size;
    const float* gc   = (const float*)d_in[0];
    const float* Hm   = (const float*)d_in[1];
    const float* Um   = (const float*)d_in[2];
    const float* vmat = (const float*)d_in[3];
    const float* um   = (const float*)d_in[4];
    const float* bmat = (const float*)d_in[5];
    const float* emb  = (const float*)d_in[6];
    float* out = (float*)d_out;

    // workspace layout (f32): hc[1024*4096] | tU[1024*512] | ug[1024*4]  (~19 MB)
    float* hc = (float*)d_ws;
    float* tU = hc + (size_t)kBT * ROWS_H;
    float* ug = tU + (size_t)kBT * ROWS_U;

    prep_kernel<<<dim3(kBT / 8, 2), 256, 0, stream>>>(gc, Hm, Um, um, hc, tU, ug);
    fused_kernel<<<dim3(kBT / 32, kV / 64), 256, 0, stream>>>(hc, tU, ug, vmat, bmat, emb, out);
    softmax_kernel<<<dim3(kBT), 256, 0, stream>>>(out);
}

// Round 2
// 1614.601 us; speedup vs baseline: 2.4959x; 2.4959x over previous
//
#include <hip/hip_runtime.h>
#include <math.h>

namespace {

using bf16x8 = __attribute__((ext_vector_type(8))) short;
using f32x4  = __attribute__((ext_vector_type(4))) float;

constexpr int kBT = 1024, kD1 = 256, kD2 = 128, kDM = 1024, kV = 32000, kK = 4;
constexpr int AR = kBT * kK;                    // 4096 rows of (bt,k)
constexpr int ROWS_H = kK * kDM;                // 4096
constexpr int ROWS_U = kK * kD2;                // 512
constexpr int ROWS_ALL = ROWS_H + ROWS_U + kK;  // 4612
constexpr int HALF_ROWS = ROWS_ALL / 2;         // 2306

__device__ __forceinline__ ushort bf16_rtn(float x) {
    union { float f; unsigned u; } v; v.f = x;
    unsigned r = v.u + 0x7fffu + ((v.u >> 16) & 1u);
    return (ushort)(r >> 16);
}
__device__ __forceinline__ float bf16f(ushort h) {
    union { unsigned u; float f; } v; v.u = ((unsigned)h) << 16; return v.f;
}
__device__ __forceinline__ void split2(float x, ushort& hi, ushort& lo) {
    hi = bf16_rtn(x);
    lo = bf16_rtn(x - bf16f(hi));
}

// ---------------------------------------------------------------------------
// prep_gemm: hc/tU/ug from gc. Outputs split bf16 (hi,lo) laid out as
// A'[(bt*4+k)][d] so the fused kernel sees one plain GEMM over 4096 rows.
// ---------------------------------------------------------------------------
__global__ __launch_bounds__(256) void prep_gemm(
    const float* __restrict__ gc, const float* __restrict__ Hm,
    const float* __restrict__ Um, const float* __restrict__ um,
    ushort* __restrict__ hch, ushort* __restrict__ hcl,
    ushort* __restrict__ tuh, ushort* __restrict__ tul,
    float* __restrict__ ug)
{
    __shared__ float sgc[8][kD1];
    const int btBase = blockIdx.x * 8;
    for (int idx = threadIdx.x; idx < 8 * kD1; idx += 256)
        sgc[idx / kD1][idx % kD1] = gc[(size_t)btBase * kD1 + idx];
    __syncthreads();

    const int rStart = blockIdx.y * HALF_ROWS;
    const int rEnd   = rStart + HALF_ROWS;
    for (int r = rStart + (int)threadIdx.x; r < rEnd; r += 256) {
        const float* wrow;
        if (r < ROWS_H)               wrow = Hm + (size_t)r * kD1;
        else if (r < ROWS_H + ROWS_U) wrow = Um + (size_t)(r - ROWS_H) * kD1;
        else                          wrow = um + (size_t)(r - ROWS_H - ROWS_U) * kD1;

        float acc[8] = {0.f,0.f,0.f,0.f,0.f,0.f,0.f,0.f};
        for (int i = 0; i < kD1; i += 4) {
            const float4 w = *reinterpret_cast<const float4*>(wrow + i);
            #pragma unroll
            for (int b = 0; b < 8; ++b) {
                const float4 g = *reinterpret_cast<const float4*>(&sgc[b][i]);
                acc[b] = fmaf(w.x, g.x, acc[b]);
                acc[b] = fmaf(w.y, g.y, acc[b]);
                acc[b] = fmaf(w.z, g.z, acc[b]);
                acc[b] = fmaf(w.w, g.w, acc[b]);
            }
        }
        #pragma unroll
        for (int b = 0; b < 8; ++b) {
            const int bt = btBase + b;
            if (r < ROWS_H) {
                const int k = r >> 10, d = r & 1023;
                const float t = tanhf(acc[b]);
                ushort hi, lo; split2(t, hi, lo);
                const size_t o = ((size_t)(bt * kK + k) << 10) + d;
                hch[o] = hi; hcl[o] = lo;
            } else if (r < ROWS_H + ROWS_U) {
                const int r2 = r - ROWS_H;
                const int k = r2 >> 7, j = r2 & 127;
                const float t = tanhf(acc[b]);
                ushort hi, lo; split2(t, hi, lo);
                const size_t o = (size_t)(bt * kK + k) * kD2 + j;
                tuh[o] = hi; tul[o] = lo;
            } else {
                ug[bt * kK + (r - ROWS_H - ROWS_U)] = acc[b];
            }
        }
    }
}

// ---------------------------------------------------------------------------
// split_kernel: elementwise fp32 -> (bf16 hi, bf16 lo). n8 = count/8.
// ---------------------------------------------------------------------------
__global__ __launch_bounds__(256) void split_kernel(
    const float* __restrict__ src, ushort* __restrict__ dh,
    ushort* __restrict__ dl, int n8)
{
    const int i = blockIdx.x * 256 + threadIdx.x;
    if (i >= n8) return;
    const float4 x0 = *reinterpret_cast<const float4*>(src + (size_t)i * 8);
    const float4 x1 = *reinterpret_cast<const float4*>(src + (size_t)i * 8 + 4);
    ushort h[8], l[8];
    split2(x0.x, h[0], l[0]); split2(x0.y, h[1], l[1]);
    split2(x0.z, h[2], l[2]); split2(x0.w, h[3], l[3]);
    split2(x1.x, h[4], l[4]); split2(x1.y, h[5], l[5]);
    split2(x1.z, h[6], l[6]); split2(x1.w, h[7], l[7]);
    uint4 hv, lv;
    hv.x = (uint)h[0] | ((uint)h[1] << 16); hv.y = (uint)h[2] | ((uint)h[3] << 16);
    hv.z = (uint)h[4] | ((uint)h[5] << 16); hv.w = (uint)h[6] | ((uint)h[7] << 16);
    lv.x = (uint)l[0] | ((uint)l[1] << 16); lv.y = (uint)l[2] | ((uint)l[3] << 16);
    lv.z = (uint)l[4] | ((uint)l[5] << 16); lv.w = (uint)l[6] | ((uint)l[7] << 16);
    *reinterpret_cast<uint4*>(dh + (size_t)i * 8) = hv;
    *reinterpret_cast<uint4*>(dl + (size_t)i * 8) = lv;
}

// ---------------------------------------------------------------------------
// fused_mfma: gate GEMM (D2) + dots GEMM (DM) on matrix cores, split-bf16.
// Block: 256 thr (4 waves). Tile: 16 bt (=64 A'rows) x 128 v.
// Wave w owns v-slice [w*32, w*32+32): acc frags [4 m][2 n], reg index = k.
// ---------------------------------------------------------------------------
template<bool ESPLIT>
__global__ __launch_bounds__(256) void fused_mfma(
    const ushort* __restrict__ hch, const ushort* __restrict__ hcl,
    const ushort* __restrict__ tuh, const ushort* __restrict__ tul,
    const ushort* __restrict__ vh,  const ushort* __restrict__ vl,
    const float* __restrict__ ug,   const float* __restrict__ bmat,
    const float* __restrict__ emb,
    const ushort* __restrict__ eh,  const ushort* __restrict__ el,
    float* __restrict__ out)
{
    __shared__ __align__(16) ushort sAh[64][40];
    __shared__ __align__(16) ushort sAl[64][40];
    __shared__ __align__(16) ushort sBh[128][40];
    __shared__ __align__(16) ushort sBl[128][40];

    const int tid  = threadIdx.x;
    const int lane = tid & 63;
    const int wave = tid >> 6;
    const int fr = lane & 15, fq = lane >> 4;
    const int btBase = blockIdx.x * 16;
    const int vBase  = blockIdx.y * 128;
    const int aRowBase = btBase * kK;
    const int woff = wave * 32;

    f32x4 acch[4][2], accl[4][2];
    const f32x4 zz = {0.f, 0.f, 0.f, 0.f};

    auto stageA = [&](const ushort* sh, const ushort* sl, int stride, int dBase) {
        const int r = tid >> 2, c8 = (tid & 3) * 8;
        const size_t go = (size_t)(aRowBase + r) * stride + dBase + c8;
        *reinterpret_cast<uint4*>(&sAh[r][c8]) = *reinterpret_cast<const uint4*>(sh + go);
        *reinterpret_cast<uint4*>(&sAl[r][c8]) = *reinterpret_cast<const uint4*>(sl + go);
    };
    auto stageB_split = [&](const ushort* sh, const ushort* sl, int stride, int dBase) {
        #pragma unroll
        for (int it = 0; it < 2; ++it) {
            const int s = tid + it * 256;
            const int r = s >> 2, c8 = (s & 3) * 8;
            const size_t go = (size_t)(vBase + r) * stride + dBase + c8;
            *reinterpret_cast<uint4*>(&sBh[r][c8]) = *reinterpret_cast<const uint4*>(sh + go);
            *reinterpret_cast<uint4*>(&sBl[r][c8]) = *reinterpret_cast<const uint4*>(sl + go);
        }
    };
    auto stageB_cvt = [&](int dBase) {
        const int r = tid >> 1, c16 = (tid & 1) * 16;
        const float* src = emb + (size_t)(vBase + r) * kDM + dBase + c16;
        uint4 H0, H1, L0, L1;
        auto cvt4 = [&](const float4 x, uint& h01, uint& h23, uint& l01, uint& l23) {
            ushort ha, hb, la, lb;
            split2(x.x, ha, la); split2(x.y, hb, lb);
            h01 = (uint)ha | ((uint)hb << 16); l01 = (uint)la | ((uint)lb << 16);
            split2(x.z, ha, la); split2(x.w, hb, lb);
            h23 = (uint)ha | ((uint)hb << 16); l23 = (uint)la | ((uint)lb << 16);
        };
        float4 x;
        x = *reinterpret_cast<const float4*>(src + 0);  cvt4(x, H0.x, H0.y, L0.x, L0.y);
        x = *reinterpret_cast<const float4*>(src + 4);  cvt4(x, H0.z, H0.w, L0.z, L0.w);
        x = *reinterpret_cast<const float4*>(src + 8);  cvt4(x, H1.x, H1.y, L1.x, L1.y);
        x = *reinterpret_cast<const float4*>(src + 12); cvt4(x, H1.z, H1.w, L1.z, L1.w);
        *reinterpret_cast<uint4*>(&sBh[r][c16])     = H0;
        *reinterpret_cast<uint4*>(&sBh[r][c16 + 8]) = H1;
        *reinterpret_cast<uint4*>(&sBl[r][c16])     = L0;
        *reinterpret_cast<uint4*>(&sBl[r][c16 + 8]) = L1;
    };

    auto mmStep = [&]() {
        bf16x8 ah[4], al[4], bh[2], bl[2];
        #pragma unroll
        for (int m = 0; m < 4; ++m) {
            ah[m] = *reinterpret_cast<const bf16x8*>(&sAh[m * 16 + fr][fq * 8]);
            al[m] = *reinterpret_cast<const bf16x8*>(&sAl[m * 16 + fr][fq * 8]);
        }
        #pragma unroll
        for (int n = 0; n < 2; ++n) {
            bh[n] = *reinterpret_cast<const bf16x8*>(&sBh[woff + n * 16 + fr][fq * 8]);
            bl[n] = *reinterpret_cast<const bf16x8*>(&sBl[woff + n * 16 + fr][fq * 8]);
        }
        #pragma unroll
        for (int m = 0; m < 4; ++m)
            #pragma unroll
            for (int n = 0; n < 2; ++n) {
                acch[m][n] = __builtin_amdgcn_mfma_f32_16x16x32_bf16(ah[m], bh[n], acch[m][n], 0, 0, 0);
                accl[m][n] = __builtin_amdgcn_mfma_f32_16x16x32_bf16(ah[m], bl[n], accl[m][n], 0, 0, 0);
                accl[m][n] = __builtin_amdgcn_mfma_f32_16x16x32_bf16(al[m], bh[n], accl[m][n], 0, 0, 0);
            }
    };

    // ---------------- phase 1: gate logits over D2 ----------------
    #pragma unroll
    for (int m = 0; m < 4; ++m)
        #pragma unroll
        for (int n = 0; n < 2; ++n) { acch[m][n] = zz; accl[m][n] = zz; }

    for (int dBase = 0; dBase < kD2; dBase += 32) {
        stageA(tuh, tul, kD2, dBase);
        stageB_split(vh, vl, kD2, dBase);
        __syncthreads();
        mmStep();
        __syncthreads();
    }

    float pi[4][2][4];
    #pragma unroll
    for (int m = 0; m < 4; ++m) {
        const int bt = btBase + m * 4 + fq;
        const float4 ugv = *reinterpret_cast<const float4*>(ug + bt * 4);
        #pragma unroll
        for (int n = 0; n < 2; ++n) {
            const int v = vBase + woff + n * 16 + fr;
            const float4 bb = *reinterpret_cast<const float4*>(bmat + (size_t)v * 4);
            const float l0 = acch[m][n][0] + accl[m][n][0] + ugv.x + bb.x;
            const float l1 = acch[m][n][1] + accl[m][n][1] + ugv.y + bb.y;
            const float l2 = acch[m][n][2] + accl[m][n][2] + ugv.z + bb.z;
            const float g0 = 1.f / (1.f + __expf(-l0));
            const float g1 = 1.f / (1.f + __expf(-l1));
            const float g2 = 1.f / (1.f + __expf(-l2));
            pi[m][n][0] = g0 * g1;
            pi[m][n][1] = g0 * (1.f - g1);
            pi[m][n][2] = (1.f - g0) * g2;
            pi[m][n][3] = (1.f - g0) * (1.f - g2);
        }
    }

    // ---------------- phase 2: dots over DM ----------------
    #pragma unroll
    for (int m = 0; m < 4; ++m)
        #pragma unroll
        for (int n = 0; n < 2; ++n) { acch[m][n] = zz; accl[m][n] = zz; }

    for (int dBase = 0; dBase < kDM; dBase += 32) {
        stageA(hch, hcl, kDM, dBase);
        if constexpr (ESPLIT) stageB_split(eh, el, kDM, dBase);
        else                  stageB_cvt(dBase);
        __syncthreads();
        mmStep();
        __syncthreads();
    }

    // ---------------- epilogue: logits ----------------
    #pragma unroll
    for (int m = 0; m < 4; ++m) {
        const int bt = btBase + m * 4 + fq;
        #pragma unroll
        for (int n = 0; n < 2; ++n) {
            const int v = vBase + woff + n * 16 + fr;
            float lg = 0.f;
            #pragma unroll
            for (int k = 0; k < 4; ++k)
                lg += pi[m][n][k] * (acch[m][n][k] + accl[m][n][k]);
            out[(size_t)bt * kV + v] = lg;
        }
    }
}

// ---------------------------------------------------------------------------
// softmax over V per row, in place.
// ---------------------------------------------------------------------------
__global__ __launch_bounds__(256) void softmax_kernel(float* __restrict__ out)
{
    __shared__ float red[4];
    float* row = out + (size_t)blockIdx.x * kV;
    const int tid = threadIdx.x;

    float mx = -1e30f;
    for (int i = tid * 4; i < kV; i += 1024) {
        const float4 x = *reinterpret_cast<const float4*>(row + i);
        mx = fmaxf(mx, fmaxf(fmaxf(x.x, x.y), fmaxf(x.z, x.w)));
    }
    #pragma unroll
    for (int o = 1; o < 64; o <<= 1) mx = fmaxf(mx, __shfl_xor(mx, o));
    if ((tid & 63) == 0) red[tid >> 6] = mx;
    __syncthreads();
    mx = fmaxf(fmaxf(red[0], red[1]), fmaxf(red[2], red[3]));
    __syncthreads();

    float s = 0.f;
    for (int i = tid * 4; i < kV; i += 1024) {
        const float4 x = *reinterpret_cast<const float4*>(row + i);
        s += __expf(x.x - mx) + __expf(x.y - mx) + __expf(x.z - mx) + __expf(x.w - mx);
    }
    #pragma unroll
    for (int o = 1; o < 64; o <<= 1) s += __shfl_xor(s, o);
    if ((tid & 63) == 0) red[tid >> 6] = s;
    __syncthreads();
    s = red[0] + red[1] + red[2] + red[3];
    const float inv = 1.f / s;

    for (int i = tid * 4; i < kV; i += 1024) {
        const float4 x = *reinterpret_cast<const float4*>(row + i);
        float4 y;
        y.x = __expf(x.x - mx) * inv;
        y.y = __expf(x.y - mx) * inv;
        y.z = __expf(x.z - mx) * inv;
        y.w = __expf(x.w - mx) * inv;
        *reinterpret_cast<float4*>(row + i) = y;
    }
}

} // namespace

extern "C" void kernel_launch(void* const* d_in, const int* in_sizes, int n_in,
                              void* d_out, int out_size, void* d_ws, size_t ws_size,
                              hipStream_t stream)
{
    (void)in_sizes; (void)n_in; (void)out_size;
    const float* gc   = (const float*)d_in[0];
    const float* Hm   = (const float*)d_in[1];
    const float* Um   = (const float*)d_in[2];
    const float* vmat = (const float*)d_in[3];
    const float* um   = (const float*)d_in[4];
    const float* bmat = (const float*)d_in[5];
    const float* emb  = (const float*)d_in[6];
    float* out = (float*)d_out;

    size_t off = 0;
    auto take = [&](size_t bytes) -> char* {
        char* p = (char*)d_ws + off;
        off += (bytes + 255) & ~(size_t)255;
        return p;
    };
    ushort* hch = (ushort*)take((size_t)AR * kDM * 2);
    ushort* hcl = (ushort*)take((size_t)AR * kDM * 2);
    ushort* tuh = (ushort*)take((size_t)AR * kD2 * 2);
    ushort* tul = (ushort*)take((size_t)AR * kD2 * 2);
    ushort* vh  = (ushort*)take((size_t)kV * kD2 * 2);
    ushort* vl  = (ushort*)take((size_t)kV * kD2 * 2);
    float*  ug  = (float*) take((size_t)AR * 4);
    ushort* eh  = (ushort*)take((size_t)kV * kDM * 2);
    ushort* el  = (ushort*)take((size_t)kV * kDM * 2);
    const bool esplit = (ws_size >= off);

    prep_gemm<<<dim3(kBT / 8, 2), 256, 0, stream>>>(gc, Hm, Um, um, hch, hcl, tuh, tul, ug);
    split_kernel<<<(kV * kD2 / 8 + 255) / 256, 256, 0, stream>>>(vmat, vh, vl, kV * kD2 / 8);
    if (esplit) {
        split_kernel<<<(kV * kDM / 8 + 255) / 256, 256, 0, stream>>>(emb, eh, el, kV * kDM / 8);
        fused_mfma<true><<<dim3(kBT / 16, kV / 128), 256, 0, stream>>>(
            hch, hcl, tuh, tul, vh, vl, ug, bmat, emb, eh, el, out);
    } else {
        fused_mfma<false><<<dim3(kBT / 16, kV / 128), 256, 0, stream>>>(
            hch, hcl, tuh, tul, vh, vl, ug, bmat, emb, eh, el, out);
    }
    softmax_kernel<<<dim3(kBT), 256, 0, stream>>>(out);
}

// Round 3
// 576.410 us; speedup vs baseline: 6.9913x; 2.8011x over previous
//
#include <hip/hip_runtime.h>
#include <math.h>

namespace {

typedef _Float16 f16;
typedef _Float16 f16x8 __attribute__((ext_vector_type(8)));
typedef float    f32x4 __attribute__((ext_vector_type(4)));

constexpr int kBT = 1024, kD1 = 256, kD2 = 128, kDM = 1024, kV = 32000, kK = 4;
constexpr int AR = kBT * kK;                    // 4096 rows of (bt,k)
constexpr int ROWS_H = kK * kDM;                // 4096
constexpr int ROWS_U = kK * kD2;                // 512
constexpr int ROWS_ALL = ROWS_H + ROWS_U + kK;  // 4612
constexpr int HALF_ROWS = ROWS_ALL / 2;         // 2306

// ---------------------------------------------------------------------------
// prep_gemm: hc/tU/ug from gc (fp32 accumulate, fp16 store).
// hc layout: [(bt*4+k)][d] (stride kDM); tU: [(bt*4+k)][j] (stride kD2).
// ---------------------------------------------------------------------------
__global__ __launch_bounds__(256) void prep_gemm(
    const float* __restrict__ gc, const float* __restrict__ Hm,
    const float* __restrict__ Um, const float* __restrict__ um,
    f16* __restrict__ hc, f16* __restrict__ tu, float* __restrict__ ug)
{
    __shared__ float sgc[8][kD1];
    const int btBase = blockIdx.x * 8;
    for (int idx = threadIdx.x; idx < 8 * kD1; idx += 256)
        sgc[idx / kD1][idx % kD1] = gc[(size_t)btBase * kD1 + idx];
    __syncthreads();

    const int rStart = blockIdx.y * HALF_ROWS;
    const int rEnd   = rStart + HALF_ROWS;
    for (int r = rStart + (int)threadIdx.x; r < rEnd; r += 256) {
        const float* wrow;
        if (r < ROWS_H)               wrow = Hm + (size_t)r * kD1;
        else if (r < ROWS_H + ROWS_U) wrow = Um + (size_t)(r - ROWS_H) * kD1;
        else                          wrow = um + (size_t)(r - ROWS_H - ROWS_U) * kD1;

        float acc[8] = {0.f,0.f,0.f,0.f,0.f,0.f,0.f,0.f};
        for (int i = 0; i < kD1; i += 4) {
            const float4 w = *reinterpret_cast<const float4*>(wrow + i);
            #pragma unroll
            for (int b = 0; b < 8; ++b) {
                const float4 g = *reinterpret_cast<const float4*>(&sgc[b][i]);
                acc[b] = fmaf(w.x, g.x, acc[b]);
                acc[b] = fmaf(w.y, g.y, acc[b]);
                acc[b] = fmaf(w.z, g.z, acc[b]);
                acc[b] = fmaf(w.w, g.w, acc[b]);
            }
        }
        #pragma unroll
        for (int b = 0; b < 8; ++b) {
            const int bt = btBase + b;
            if (r < ROWS_H) {
                const int k = r >> 10, d = r & 1023;
                hc[((size_t)(bt * kK + k) << 10) + d] = (f16)tanhf(acc[b]);
            } else if (r < ROWS_H + ROWS_U) {
                const int r2 = r - ROWS_H;
                const int k = r2 >> 7, j = r2 & 127;
                tu[(size_t)(bt * kK + k) * kD2 + j] = (f16)tanhf(acc[b]);
            } else {
                ug[bt * kK + (r - ROWS_H - ROWS_U)] = acc[b];
            }
        }
    }
}

// ---------------------------------------------------------------------------
// cvt_kernel: fp32 -> fp16, 8 elems/thread.
// ---------------------------------------------------------------------------
__global__ __launch_bounds__(256) void cvt_kernel(
    const float* __restrict__ src, f16* __restrict__ dst, int n8)
{
    const int i = blockIdx.x * 256 + threadIdx.x;
    if (i >= n8) return;
    const float4 x0 = *reinterpret_cast<const float4*>(src + (size_t)i * 8);
    const float4 x1 = *reinterpret_cast<const float4*>(src + (size_t)i * 8 + 4);
    union { f16 h[8]; uint4 v; } u;
    u.h[0] = (f16)x0.x; u.h[1] = (f16)x0.y; u.h[2] = (f16)x0.z; u.h[3] = (f16)x0.w;
    u.h[4] = (f16)x1.x; u.h[5] = (f16)x1.y; u.h[6] = (f16)x1.z; u.h[7] = (f16)x1.w;
    *reinterpret_cast<uint4*>(dst + (size_t)i * 8) = u.v;
}

// ---------------------------------------------------------------------------
// fused_mfma: gates (K=128) + dots (K=1024) fp16 MFMA GEMM, m97 structure.
// Block 256 thr (4 waves), tile 128 A-rows x 128 v, BK=64.
// LDS [128][64] f16 per matrix, XOR-swizzled 16B slots: phys = slot^(row&7).
// Staged with global_load_lds(16B): linear LDS dest, inverse-swizzled source.
// Wave (wrow,wcol) owns 64x64; acc[m][n] reg j = mixture component k=j.
// ---------------------------------------------------------------------------
__global__ __launch_bounds__(256, 2) void fused_mfma(
    const f16* __restrict__ hc,  const f16* __restrict__ tu,
    const f16* __restrict__ v16, const f16* __restrict__ e16,
    const float* __restrict__ ug, const float* __restrict__ bmat,
    float* __restrict__ out)
{
    __shared__ __align__(16) f16 sA[128 * 64];
    __shared__ __align__(16) f16 sB[128 * 64];

    const int tid  = threadIdx.x;
    const int lane = tid & 63;
    const int wave = tid >> 6;
    const int fr = lane & 15, fq = lane >> 4;
    const int wrow = wave >> 1, wcol = wave & 1;
    const int aRowBase = blockIdx.x * 128;
    const int vBase    = blockIdx.y * 128;

    // staging geometry: chunk = 8 rows x 128B; lane l -> row srow, phys slot l&7,
    // which must hold logical slot (l&7)^(srow&7).
    const int srow = lane >> 3;
    const int scol = ((lane & 7) ^ srow) * 8;   // logical column (f16 units)

    auto stage = [&](const f16* __restrict__ g, f16* ldsbuf, int rowBase,
                     int stride, int dBase) {
        #pragma unroll
        for (int i = 0; i < 4; ++i) {
            const int c = wave * 4 + i;                 // chunk 0..15
            const f16* src = g + (size_t)(rowBase + c * 8 + srow) * stride + dBase + scol;
            f16* dst = ldsbuf + c * 512;                // 1024 B per chunk
            __builtin_amdgcn_global_load_lds(
                (const __attribute__((address_space(1))) void*)src,
                (__attribute__((address_space(3))) void*)dst, 16, 0, 0);
        }
    };

    auto mmStep = [&](f32x4 (&acc)[4][4]) {
        #pragma unroll
        for (int kk = 0; kk < 2; ++kk) {
            f16x8 a[4], b[4];
            #pragma unroll
            for (int m = 0; m < 4; ++m) {
                const int r = wrow * 64 + m * 16 + fr;
                const int ps = (kk * 4 + fq) ^ (r & 7);
                a[m] = *reinterpret_cast<const f16x8*>(sA + r * 64 + ps * 8);
            }
            #pragma unroll
            for (int n = 0; n < 4; ++n) {
                const int r = wcol * 64 + n * 16 + fr;
                const int ps = (kk * 4 + fq) ^ (r & 7);
                b[n] = *reinterpret_cast<const f16x8*>(sB + r * 64 + ps * 8);
            }
            #pragma unroll
            for (int m = 0; m < 4; ++m)
                #pragma unroll
                for (int n = 0; n < 4; ++n)
                    acc[m][n] = __builtin_amdgcn_mfma_f32_16x16x32_f16(
                        a[m], b[n], acc[m][n], 0, 0, 0);
        }
    };

    f32x4 acc[4][4];
    const f32x4 zz = {0.f, 0.f, 0.f, 0.f};

    // ---------------- phase 1: gate logits over D2=128 ----------------
    #pragma unroll
    for (int m = 0; m < 4; ++m)
        #pragma unroll
        for (int n = 0; n < 4; ++n) acc[m][n] = zz;

    for (int t = 0; t < kD2 / 64; ++t) {
        stage(tu,  sA, aRowBase, kD2, t * 64);
        stage(v16, sB, vBase,    kD2, t * 64);
        __syncthreads();
        mmStep(acc);
        __syncthreads();
    }

    float pi[4][4][4];
    #pragma unroll
    for (int m = 0; m < 4; ++m) {
        const int bt = blockIdx.x * 32 + wrow * 16 + m * 4 + fq;
        const float4 ugv = *reinterpret_cast<const float4*>(ug + bt * 4);
        #pragma unroll
        for (int n = 0; n < 4; ++n) {
            const int v = vBase + wcol * 64 + n * 16 + fr;
            const float4 bb = *reinterpret_cast<const float4*>(bmat + (size_t)v * 4);
            const float l0 = acc[m][n][0] + ugv.x + bb.x;
            const float l1 = acc[m][n][1] + ugv.y + bb.y;
            const float l2 = acc[m][n][2] + ugv.z + bb.z;
            const float g0 = 1.f / (1.f + __expf(-l0));
            const float g1 = 1.f / (1.f + __expf(-l1));
            const float g2 = 1.f / (1.f + __expf(-l2));
            pi[m][n][0] = g0 * g1;
            pi[m][n][1] = g0 * (1.f - g1);
            pi[m][n][2] = (1.f - g0) * g2;
            pi[m][n][3] = (1.f - g0) * (1.f - g2);
        }
    }

    // ---------------- phase 2: dots over DM=1024 ----------------
    #pragma unroll
    for (int m = 0; m < 4; ++m)
        #pragma unroll
        for (int n = 0; n < 4; ++n) acc[m][n] = zz;

    for (int t = 0; t < kDM / 64; ++t) {
        stage(hc,  sA, aRowBase, kDM, t * 64);
        stage(e16, sB, vBase,    kDM, t * 64);
        __syncthreads();
        mmStep(acc);
        __syncthreads();
    }

    // ---------------- epilogue: logits ----------------
    #pragma unroll
    for (int m = 0; m < 4; ++m) {
        const int bt = blockIdx.x * 32 + wrow * 16 + m * 4 + fq;
        #pragma unroll
        for (int n = 0; n < 4; ++n) {
            const int v = vBase + wcol * 64 + n * 16 + fr;
            float lg = pi[m][n][0] * acc[m][n][0] + pi[m][n][1] * acc[m][n][1]
                     + pi[m][n][2] * acc[m][n][2] + pi[m][n][3] * acc[m][n][3];
            out[(size_t)bt * kV + v] = lg;
        }
    }
}

// ---------------------------------------------------------------------------
// softmax over V per row, in place.
// ---------------------------------------------------------------------------
__global__ __launch_bounds__(256) void softmax_kernel(float* __restrict__ out)
{
    __shared__ float red[4];
    float* row = out + (size_t)blockIdx.x * kV;
    const int tid = threadIdx.x;

    float mx = -1e30f;
    for (int i = tid * 4; i < kV; i += 1024) {
        const float4 x = *reinterpret_cast<const float4*>(row + i);
        mx = fmaxf(mx, fmaxf(fmaxf(x.x, x.y), fmaxf(x.z, x.w)));
    }
    #pragma unroll
    for (int o = 1; o < 64; o <<= 1) mx = fmaxf(mx, __shfl_xor(mx, o));
    if ((tid & 63) == 0) red[tid >> 6] = mx;
    __syncthreads();
    mx = fmaxf(fmaxf(red[0], red[1]), fmaxf(red[2], red[3]));
    __syncthreads();

    float s = 0.f;
    for (int i = tid * 4; i < kV; i += 1024) {
        const float4 x = *reinterpret_cast<const float4*>(row + i);
        s += __expf(x.x - mx) + __expf(x.y - mx) + __expf(x.z - mx) + __expf(x.w - mx);
    }
    #pragma unroll
    for (int o = 1; o < 64; o <<= 1) s += __shfl_xor(s, o);
    if ((tid & 63) == 0) red[tid >> 6] = s;
    __syncthreads();
    s = red[0] + red[1] + red[2] + red[3];
    const float inv = 1.f / s;

    for (int i = tid * 4; i < kV; i += 1024) {
        const float4 x = *reinterpret_cast<const float4*>(row + i);
        float4 y;
        y.x = __expf(x.x - mx) * inv;
        y.y = __expf(x.y - mx) * inv;
        y.z = __expf(x.z - mx) * inv;
        y.w = __expf(x.w - mx) * inv;
        *reinterpret_cast<float4*>(row + i) = y;
    }
}

} // namespace

extern "C" void kernel_launch(void* const* d_in, const int* in_sizes, int n_in,
                              void* d_out, int out_size, void* d_ws, size_t ws_size,
                              hipStream_t stream)
{
    (void)in_sizes; (void)n_in; (void)out_size; (void)ws_size;
    const float* gc   = (const float*)d_in[0];
    const float* Hm   = (const float*)d_in[1];
    const float* Um   = (const float*)d_in[2];
    const float* vmat = (const float*)d_in[3];
    const float* um   = (const float*)d_in[4];
    const float* bmat = (const float*)d_in[5];
    const float* emb  = (const float*)d_in[6];
    float* out = (float*)d_out;

    size_t off = 0;
    auto take = [&](size_t bytes) -> char* {
        char* p = (char*)d_ws + off;
        off += (bytes + 255) & ~(size_t)255;
        return p;
    };
    f16*   hc  = (f16*)  take((size_t)AR * kDM * 2);   // 8 MB
    f16*   tu  = (f16*)  take((size_t)AR * kD2 * 2);   // 1 MB
    f16*   v16 = (f16*)  take((size_t)kV * kD2 * 2);   // 8 MB
    f16*   e16 = (f16*)  take((size_t)kV * kDM * 2);   // 64 MB
    float* ug  = (float*)take((size_t)AR * 4);

    prep_gemm<<<dim3(kBT / 8, 2), 256, 0, stream>>>(gc, Hm, Um, um, hc, tu, ug);
    cvt_kernel<<<(kV * kD2 / 8 + 255) / 256, 256, 0, stream>>>(vmat, v16, kV * kD2 / 8);
    cvt_kernel<<<(kV * kDM / 8 + 255) / 256, 256, 0, stream>>>(emb, e16, kV * kDM / 8);
    fused_mfma<<<dim3(AR / 128, kV / 128), 256, 0, stream>>>(
        hc, tu, v16, e16, ug, bmat, out);
    softmax_kernel<<<dim3(kBT), 256, 0, stream>>>(out);
}